// Round 1
// baseline (1500.065 us; speedup 1.0000x reference)
//
#include <hip/hip_runtime.h>
#include <stdint.h>

// Problem constants (from reference)
constexpr int kN = 100000;   // nodes
constexpr int kE = 1600000;  // edges
constexpr int kP = 500000;   // pairs
constexpr int NBS = (kN + 255) / 256;  // scan blocks = 391

// ---------------------------------------------------------------------------
// CSR build: degree histogram -> exclusive scan -> fill src-sorted lists
// ---------------------------------------------------------------------------
__global__ void deg_kernel(const int* __restrict__ dst, int* __restrict__ deg) {
    int e = blockIdx.x * blockDim.x + threadIdx.x;
    if (e < kE) atomicAdd(&deg[dst[e]], 1);
}

__global__ void scan_block_sums(const int* __restrict__ deg, int* __restrict__ bsum) {
    __shared__ int red[256];
    int t = threadIdx.x;
    int i = blockIdx.x * 256 + t;
    red[t] = (i < kN) ? deg[i] : 0;
    __syncthreads();
    for (int s = 128; s > 0; s >>= 1) {
        if (t < s) red[t] += red[t + s];
        __syncthreads();
    }
    if (t == 0) bsum[blockIdx.x] = red[0];
}

__global__ void scan_bsums(const int* __restrict__ bsum, int* __restrict__ boff) {
    __shared__ int sm[512];
    int t = threadIdx.x;
    int orig = (t < NBS) ? bsum[t] : 0;
    sm[t] = orig;
    __syncthreads();
    for (int d = 1; d < 512; d <<= 1) {
        int u = (t >= d) ? sm[t - d] : 0;
        __syncthreads();
        sm[t] += u;
        __syncthreads();
    }
    if (t < NBS) boff[t] = sm[t] - orig;  // exclusive
}

__global__ void scan_write(const int* __restrict__ deg, const int* __restrict__ boff,
                           int* __restrict__ row_start, int* __restrict__ cursor) {
    __shared__ int sm[256];
    int t = threadIdx.x;
    int i = blockIdx.x * 256 + t;
    int v = (i < kN) ? deg[i] : 0;
    sm[t] = v;
    __syncthreads();
    for (int d = 1; d < 256; d <<= 1) {
        int u = (t >= d) ? sm[t - d] : 0;
        __syncthreads();
        sm[t] += u;
        __syncthreads();
    }
    int excl = sm[t] - v + boff[blockIdx.x];
    if (i < kN) { row_start[i] = excl; cursor[i] = excl; }
    if (i == kN - 1) row_start[kN] = excl + v;
}

__global__ void fill_kernel(const int* __restrict__ src, const int* __restrict__ dst,
                            int* __restrict__ cursor, int* __restrict__ srcs) {
    int e = blockIdx.x * blockDim.x + threadIdx.x;
    if (e < kE) {
        int p = atomicAdd(&cursor[dst[e]], 1);
        srcs[p] = src[e];
    }
}

// ---------------------------------------------------------------------------
// Fused SAGEConv: out = act( mean_aggr(xin) @ Wl^T + bias + xin @ Wr^T )
// Tile: 48 nodes/block, 256 threads. LDS A-tile [48][260] (49.9KB) -> 3 blk/CU
// ---------------------------------------------------------------------------
constexpr int CT  = 48;    // node tile
constexpr int ALD = 260;   // A-tile leading dim (256 + 4 pad -> 2-way banks, free)
constexpr int OLD = 132;   // output staging leading dim (16B-aligned rows)

template <bool RELU>
__global__ __launch_bounds__(256, 3) void conv_kernel(
    const float* __restrict__ xin,
    const int* __restrict__ row_start,
    const int* __restrict__ srcs,
    const float* __restrict__ Wl,
    const float* __restrict__ Wr,
    const float* __restrict__ bias,
    float* __restrict__ out)
{
    __shared__ float smem[CT * ALD];
    const int t  = threadIdx.x;
    const int nb = blockIdx.x * CT;

    // Phase 1a: gather-mean neighbor rows -> A[:, 0:128]
    {
        const int c   = (t & 31) * 4;   // dim offset (float4)
        const int sub = t >> 5;         // 0..7 (8 rows in flight)
        for (int k = 0; k < CT / 8; k++) {
            const int ln = k * 8 + sub;
            const int n  = nb + ln;
            float4 acc = make_float4(0.f, 0.f, 0.f, 0.f);
            if (n < kN) {
                const int j0 = row_start[n], j1 = row_start[n + 1];
                for (int j = j0; j < j1; j++) {
                    const float4 v = *(const float4*)&xin[(size_t)srcs[j] * 128 + c];
                    acc.x += v.x; acc.y += v.y; acc.z += v.z; acc.w += v.w;
                }
                const int dg = j1 - j0;
                if (dg > 1) {
                    const float inv = 1.0f / (float)dg;
                    acc.x *= inv; acc.y *= inv; acc.z *= inv; acc.w *= inv;
                }
            }
            *(float4*)&smem[ln * ALD + c] = acc;
        }
        // Phase 1b: root features -> A[:, 128:256]
        for (int k = 0; k < CT / 8; k++) {
            const int ln = k * 8 + sub;
            const int n  = nb + ln;
            float4 v = make_float4(0.f, 0.f, 0.f, 0.f);
            if (n < kN) v = *(const float4*)&xin[(size_t)n * 128 + c];
            *(float4*)&smem[ln * ALD + 128 + c] = v;
        }
    }
    __syncthreads();

    // Phase 2: register-tiled GEMM. Thread: 3 nodes x 8 outputs.
    const int tn = t & 15;   // node sub-index (adjacent lanes -> LDS, 2-way free)
    const int to = t >> 4;   // output group (16-lane broadcast of W loads)
    float acc[3][8];
    int olist[8];
#pragma unroll
    for (int jo = 0; jo < 8; jo++) {
        const int o = to + 16 * jo;
        olist[jo] = o;
        const float b = bias[o];
#pragma unroll
        for (int i = 0; i < 3; i++) acc[i][jo] = b;
    }
    for (int k = 0; k < 256; k += 4) {
        const float* __restrict__ Wsel = (k < 128) ? Wl : Wr;
        const int kk = k & 127;
        float4 a4[3];
#pragma unroll
        for (int i = 0; i < 3; i++)
            a4[i] = *(const float4*)&smem[(tn + 16 * i) * ALD + k];
#pragma unroll
        for (int jo = 0; jo < 8; jo++) {
            const float4 w4 = *(const float4*)&Wsel[olist[jo] * 128 + kk];
#pragma unroll
            for (int i = 0; i < 3; i++) {
                acc[i][jo] += a4[i].x * w4.x;
                acc[i][jo] += a4[i].y * w4.y;
                acc[i][jo] += a4[i].z * w4.z;
                acc[i][jo] += a4[i].w * w4.w;
            }
        }
    }
    __syncthreads();

    // Phase 3: stage + coalesced store
#pragma unroll
    for (int jo = 0; jo < 8; jo++)
#pragma unroll
        for (int i = 0; i < 3; i++) {
            float v = acc[i][jo];
            if (RELU) v = fmaxf(v, 0.f);
            smem[(tn + 16 * i) * OLD + olist[jo]] = v;
        }
    __syncthreads();
    {
        const int c   = (t & 31) * 4;
        const int sub = t >> 5;
        for (int k = 0; k < CT / 8; k++) {
            const int ln = k * 8 + sub;
            const int n  = nb + ln;
            if (n < kN)
                *(float4*)&out[(size_t)n * 128 + c] = *(const float4*)&smem[ln * OLD + c];
        }
    }
}

// ---------------------------------------------------------------------------
// Fused decoder: hp = z[a]*z[b]; y1 = relu(hp@Wm1^T+bm1);
// y2 = relu(y1@Wm2^T+bm2); out = y2.Wm3 + bm3.  48 pairs/block.
// LDS: hp[48][132] + y1[48][132] = 50.7KB -> 3 blk/CU. y2 reuses hp region.
// ---------------------------------------------------------------------------
constexpr int PT  = 48;
constexpr int HLD = 132;

__global__ __launch_bounds__(256, 3) void decoder_kernel(
    const float* __restrict__ z,
    const int* __restrict__ pairs,
    const float* __restrict__ Wm1, const float* __restrict__ bm1,
    const float* __restrict__ Wm2, const float* __restrict__ bm2,
    const float* __restrict__ Wm3, const float* __restrict__ bm3,
    float* __restrict__ outv)
{
    __shared__ float hp[PT * HLD];
    __shared__ float y1[PT * HLD];
    const int t  = threadIdx.x;
    const int pb = blockIdx.x * PT;

    // P1: hp = z[a] * z[b]
    {
        const int c   = (t & 31) * 4;
        const int sub = t >> 5;
        for (int k = 0; k < PT / 8; k++) {
            const int lp = k * 8 + sub;
            const int gp = pb + lp;
            float4 v = make_float4(0.f, 0.f, 0.f, 0.f);
            if (gp < kP) {
                const int a = pairs[gp * 2];
                const int b = pairs[gp * 2 + 1];
                const float4 za = *(const float4*)&z[(size_t)a * 128 + c];
                const float4 zb = *(const float4*)&z[(size_t)b * 128 + c];
                v = make_float4(za.x * zb.x, za.y * zb.y, za.z * zb.z, za.w * zb.w);
            }
            *(float4*)&hp[lp * HLD + c] = v;
        }
    }
    __syncthreads();

    const int tn = t & 15;
    const int to = t >> 4;

    // P2: y1 = relu(hp @ Wm1^T + bm1)   [48 x 128]
    {
        float acc[3][8];
        int olist[8];
#pragma unroll
        for (int jo = 0; jo < 8; jo++) {
            const int o = to + 16 * jo;
            olist[jo] = o;
            const float b = bm1[o];
#pragma unroll
            for (int i = 0; i < 3; i++) acc[i][jo] = b;
        }
        for (int k = 0; k < 128; k += 4) {
            float4 a4[3];
#pragma unroll
            for (int i = 0; i < 3; i++)
                a4[i] = *(const float4*)&hp[(tn + 16 * i) * HLD + k];
#pragma unroll
            for (int jo = 0; jo < 8; jo++) {
                const float4 w4 = *(const float4*)&Wm1[olist[jo] * 128 + k];
#pragma unroll
                for (int i = 0; i < 3; i++) {
                    acc[i][jo] += a4[i].x * w4.x;
                    acc[i][jo] += a4[i].y * w4.y;
                    acc[i][jo] += a4[i].z * w4.z;
                    acc[i][jo] += a4[i].w * w4.w;
                }
            }
        }
#pragma unroll
        for (int jo = 0; jo < 8; jo++)
#pragma unroll
            for (int i = 0; i < 3; i++)
                y1[(tn + 16 * i) * HLD + olist[jo]] = fmaxf(acc[i][jo], 0.f);
    }
    __syncthreads();

    // P3: y2 = relu(y1 @ Wm2^T + bm2)   [48 x 64], written into hp region
    {
        float acc[3][4];
        int olist[4];
#pragma unroll
        for (int jo = 0; jo < 4; jo++) {
            const int o = to + 16 * jo;
            olist[jo] = o;
            const float b = bm2[o];
#pragma unroll
            for (int i = 0; i < 3; i++) acc[i][jo] = b;
        }
        for (int k = 0; k < 128; k += 4) {
            float4 a4[3];
#pragma unroll
            for (int i = 0; i < 3; i++)
                a4[i] = *(const float4*)&y1[(tn + 16 * i) * HLD + k];
#pragma unroll
            for (int jo = 0; jo < 4; jo++) {
                const float4 w4 = *(const float4*)&Wm2[olist[jo] * 128 + k];
#pragma unroll
                for (int i = 0; i < 3; i++) {
                    acc[i][jo] += a4[i].x * w4.x;
                    acc[i][jo] += a4[i].y * w4.y;
                    acc[i][jo] += a4[i].z * w4.z;
                    acc[i][jo] += a4[i].w * w4.w;
                }
            }
        }
#pragma unroll
        for (int jo = 0; jo < 4; jo++)
#pragma unroll
            for (int i = 0; i < 3; i++)
                hp[(tn + 16 * i) * HLD + olist[jo]] = fmaxf(acc[i][jo], 0.f);
    }
    __syncthreads();

    // P4: out = y2 . Wm3 + bm3 (4 lanes per pair, quad shuffle reduce)
    if (t < PT * 4) {
        const int p = t >> 2, q = t & 3;
        float s = 0.f;
#pragma unroll
        for (int dd = 0; dd < 16; dd++) {
            const int d = q * 16 + dd;
            s += hp[p * HLD + d] * Wm3[d];
        }
        s += __shfl_xor(s, 1);
        s += __shfl_xor(s, 2);
        const int gp = pb + p;
        if (q == 0 && gp < kP) outv[gp] = s + bm3[0];
    }
}

// ---------------------------------------------------------------------------
extern "C" void kernel_launch(void* const* d_in, const int* in_sizes, int n_in,
                              void* d_out, int out_size, void* d_ws, size_t ws_size,
                              hipStream_t stream) {
    const float* x   = (const float*)d_in[0];
    const int*   src = (const int*)d_in[1];        // edge_index row 0
    const int*   dst = src + kE;                   // edge_index row 1
    const int*   ep  = (const int*)d_in[2];        // [P,2] interleaved
    const float* W1l = (const float*)d_in[3];
    const float* b1l = (const float*)d_in[4];
    const float* W1r = (const float*)d_in[5];
    const float* W2l = (const float*)d_in[6];
    const float* b2l = (const float*)d_in[7];
    const float* W2r = (const float*)d_in[8];
    const float* Wm1 = (const float*)d_in[9];
    const float* bm1 = (const float*)d_in[10];
    const float* Wm2 = (const float*)d_in[11];
    const float* bm2 = (const float*)d_in[12];
    const float* Wm3 = (const float*)d_in[13];
    const float* bm3 = (const float*)d_in[14];
    float* outv = (float*)d_out;

    // Workspace carve-up (~110 MB total)
    char* ws = (char*)d_ws;
    size_t off = 0;
    auto alloc = [&](size_t bytes) -> void* {
        void* p = ws + off;
        off += bytes;
        off = (off + 255) & ~(size_t)255;
        return p;
    };
    int*   deg       = (int*)alloc((size_t)kN * 4);
    int*   row_start = (int*)alloc((size_t)(kN + 1) * 4);
    int*   cursor    = (int*)alloc((size_t)kN * 4);
    int*   bsum      = (int*)alloc(512 * 4);
    int*   boff      = (int*)alloc(512 * 4);
    int*   srcs      = (int*)alloc((size_t)kE * 4);
    float* h         = (float*)alloc((size_t)kN * 128 * 4);
    float* zz        = (float*)alloc((size_t)kN * 128 * 4);

    // CSR build
    hipMemsetAsync(deg, 0, (size_t)kN * sizeof(int), stream);
    deg_kernel<<<(kE + 255) / 256, 256, 0, stream>>>(dst, deg);
    scan_block_sums<<<NBS, 256, 0, stream>>>(deg, bsum);
    scan_bsums<<<1, 512, 0, stream>>>(bsum, boff);
    scan_write<<<NBS, 256, 0, stream>>>(deg, boff, row_start, cursor);
    fill_kernel<<<(kE + 255) / 256, 256, 0, stream>>>(src, dst, cursor, srcs);

    // Two SAGEConv layers
    const int convGrid = (kN + CT - 1) / CT;
    conv_kernel<true><<<convGrid, 256, 0, stream>>>(x, row_start, srcs, W1l, W1r, b1l, h);
    conv_kernel<false><<<convGrid, 256, 0, stream>>>(h, row_start, srcs, W2l, W2r, b2l, zz);

    // Fused MLP decoder
    decoder_kernel<<<(kP + PT - 1) / PT, 256, 0, stream>>>(
        zz, ep, Wm1, bm1, Wm2, bm2, Wm3, bm3, outv);
}

// Round 2
// 1108.315 us; speedup vs baseline: 1.3535x; 1.3535x over previous
//
#include <hip/hip_runtime.h>
#include <stdint.h>

typedef _Float16 half8 __attribute__((ext_vector_type(8)));
typedef float float4v __attribute__((ext_vector_type(4)));

// Problem constants
constexpr int kN = 100000;   // nodes
constexpr int kE = 1600000;  // edges
constexpr int kP = 500000;   // pairs
constexpr int NBS = (kN + 255) / 256;  // scan blocks = 391

// ---------------------------------------------------------------------------
// CSR build (unchanged from R1)
// ---------------------------------------------------------------------------
__global__ void deg_kernel(const int* __restrict__ dst, int* __restrict__ deg) {
    int e = blockIdx.x * blockDim.x + threadIdx.x;
    if (e < kE) atomicAdd(&deg[dst[e]], 1);
}

__global__ void scan_block_sums(const int* __restrict__ deg, int* __restrict__ bsum) {
    __shared__ int red[256];
    int t = threadIdx.x;
    int i = blockIdx.x * 256 + t;
    red[t] = (i < kN) ? deg[i] : 0;
    __syncthreads();
    for (int s = 128; s > 0; s >>= 1) {
        if (t < s) red[t] += red[t + s];
        __syncthreads();
    }
    if (t == 0) bsum[blockIdx.x] = red[0];
}

__global__ void scan_bsums(const int* __restrict__ bsum, int* __restrict__ boff) {
    __shared__ int sm[512];
    int t = threadIdx.x;
    int orig = (t < NBS) ? bsum[t] : 0;
    sm[t] = orig;
    __syncthreads();
    for (int d = 1; d < 512; d <<= 1) {
        int u = (t >= d) ? sm[t - d] : 0;
        __syncthreads();
        sm[t] += u;
        __syncthreads();
    }
    if (t < NBS) boff[t] = sm[t] - orig;  // exclusive
}

__global__ void scan_write(const int* __restrict__ deg, const int* __restrict__ boff,
                           int* __restrict__ row_start, int* __restrict__ cursor) {
    __shared__ int sm[256];
    int t = threadIdx.x;
    int i = blockIdx.x * 256 + t;
    int v = (i < kN) ? deg[i] : 0;
    sm[t] = v;
    __syncthreads();
    for (int d = 1; d < 256; d <<= 1) {
        int u = (t >= d) ? sm[t - d] : 0;
        __syncthreads();
        sm[t] += u;
        __syncthreads();
    }
    int excl = sm[t] - v + boff[blockIdx.x];
    if (i < kN) { row_start[i] = excl; cursor[i] = excl; }
    if (i == kN - 1) row_start[kN] = excl + v;
}

__global__ void fill_kernel(const int* __restrict__ src, const int* __restrict__ dst,
                            int* __restrict__ cursor, int* __restrict__ srcs) {
    int e = blockIdx.x * blockDim.x + threadIdx.x;
    if (e < kE) {
        int p = atomicAdd(&cursor[dst[e]], 1);
        srcs[p] = src[e];
    }
}

// ---------------------------------------------------------------------------
// Prep: x -> fp16; weights -> combined fp16 hi/lo planes
// ---------------------------------------------------------------------------
__global__ void cvt_x_kernel(const float* __restrict__ x, _Float16* __restrict__ xh) {
    const int i = (blockIdx.x * 256 + threadIdx.x) * 8;
    if (i >= kN * 128) return;
    const float4 a = *(const float4*)&x[i];
    const float4 b = *(const float4*)&x[i + 4];
    half8 v;
    v[0] = (_Float16)a.x; v[1] = (_Float16)a.y; v[2] = (_Float16)a.z; v[3] = (_Float16)a.w;
    v[4] = (_Float16)b.x; v[5] = (_Float16)b.y; v[6] = (_Float16)b.z; v[7] = (_Float16)b.w;
    *(half8*)&xh[i] = v;
}

// CW1/CW2: [128 out][256 k] with k<128 -> Wl, k>=128 -> Wr. M1:[128][128], M2:[64][128].
__global__ void cvt_w_kernel(
    const float* __restrict__ W1l, const float* __restrict__ W1r,
    const float* __restrict__ W2l, const float* __restrict__ W2r,
    const float* __restrict__ Wm1, const float* __restrict__ Wm2,
    _Float16* __restrict__ CW1h, _Float16* __restrict__ CW1e,
    _Float16* __restrict__ CW2h, _Float16* __restrict__ CW2e,
    _Float16* __restrict__ M1h,  _Float16* __restrict__ M1e,
    _Float16* __restrict__ M2h,  _Float16* __restrict__ M2e)
{
    const int i = blockIdx.x * 256 + threadIdx.x;
    float w;
    _Float16 *ph, *pe;
    if (i < 32768) {
        const int o = i >> 8, k = i & 255;
        w = (k < 128) ? W1l[o * 128 + k] : W1r[o * 128 + k - 128];
        ph = CW1h + i; pe = CW1e + i;
    } else if (i < 65536) {
        const int j = i - 32768;
        const int o = j >> 8, k = j & 255;
        w = (k < 128) ? W2l[o * 128 + k] : W2r[o * 128 + k - 128];
        ph = CW2h + j; pe = CW2e + j;
    } else if (i < 81920) {
        const int j = i - 65536;
        w = Wm1[j]; ph = M1h + j; pe = M1e + j;
    } else if (i < 90112) {
        const int j = i - 81920;
        w = Wm2[j]; ph = M2h + j; pe = M2e + j;
    } else return;
    const _Float16 h = (_Float16)w;
    *ph = h;
    *pe = (_Float16)(w - (float)h);
}

// ---------------------------------------------------------------------------
// Fused SAGEConv (fp16 MFMA): out = act([mean_aggr(xin) | xin] @ CW^T + bias)
// CT=64 nodes/block, 256 threads (4 waves), wave w -> node rows [w*16, w*16+16)
// LDS: A-tile [64][264] fp16 = 33.8 KB -> 4 blocks/CU
// ---------------------------------------------------------------------------
constexpr int CT  = 64;
constexpr int ALD = 264;  // A-tile stride in halfs (16B-aligned rows, 2-way banks = free)
constexpr int SLD = 136;  // epilogue staging stride

template <bool RELU>
__global__ __launch_bounds__(256, 4) void conv_mfma(
    const _Float16* __restrict__ xin,
    const int* __restrict__ row_start,
    const int* __restrict__ srcs,
    const _Float16* __restrict__ Wh,  // [128][256] fp16 hi
    const _Float16* __restrict__ We,  // [128][256] fp16 lo
    const float* __restrict__ bias,
    _Float16* __restrict__ out)
{
    __shared__ __align__(16) _Float16 smem[CT * ALD];
    const int t  = threadIdx.x;
    const int nb = blockIdx.x * CT;

    // Phase 1: gather-mean (fp32 accum) + root -> fp16 A-tile [64][256]
    {
        const int c   = (t & 15) * 8;  // dim chunk (8 halfs = 16B)
        const int sub = t >> 4;        // 16 rows in flight
        for (int it = 0; it < CT / 16; it++) {
            const int ln = it * 16 + sub;
            const int n  = nb + ln;
            float accv[8];
#pragma unroll
            for (int u = 0; u < 8; u++) accv[u] = 0.f;
            half8 rv;
#pragma unroll
            for (int u = 0; u < 8; u++) rv[u] = (_Float16)0.f;
            if (n < kN) {
                const int j0 = row_start[n], j1 = row_start[n + 1];
                for (int j = j0; j < j1; j++) {
                    const half8 v = *(const half8*)&xin[(size_t)srcs[j] * 128 + c];
#pragma unroll
                    for (int u = 0; u < 8; u++) accv[u] += (float)v[u];
                }
                const int dg = j1 - j0;
                if (dg > 1) {
                    const float inv = 1.0f / (float)dg;
#pragma unroll
                    for (int u = 0; u < 8; u++) accv[u] *= inv;
                }
                rv = *(const half8*)&xin[(size_t)n * 128 + c];
            }
            half8 hv;
#pragma unroll
            for (int u = 0; u < 8; u++) hv[u] = (_Float16)accv[u];
            *(half8*)&smem[ln * ALD + c]       = hv;
            *(half8*)&smem[ln * ALD + 128 + c] = rv;
        }
    }
    __syncthreads();

    // Phase 2: MFMA GEMM. D[64][128] = A[64][256] @ W[128][256]^T
    const int w  = t >> 6;   // wave id -> M-subtile
    const int l  = t & 63;
    const int nl = l & 15;   // N-lane / M-lane
    const int q  = l >> 4;   // quad
    float4v acc[8];
#pragma unroll
    for (int nt = 0; nt < 8; nt++) {
        const float b = bias[nt * 16 + nl];
        acc[nt][0] = b; acc[nt][1] = b; acc[nt][2] = b; acc[nt][3] = b;
    }
#pragma unroll
    for (int kt = 0; kt < 8; kt++) {
        const half8 a = *(const half8*)&smem[(w * 16 + nl) * ALD + kt * 32 + q * 8];
#pragma unroll
        for (int nt = 0; nt < 8; nt++) {
            const int widx = (nt * 16 + nl) * 256 + kt * 32 + q * 8;
            const half8 bh = *(const half8*)&Wh[widx];
            const half8 be = *(const half8*)&We[widx];
            acc[nt] = __builtin_amdgcn_mfma_f32_16x16x32_f16(a, bh, acc[nt], 0, 0, 0);
            acc[nt] = __builtin_amdgcn_mfma_f32_16x16x32_f16(a, be, acc[nt], 0, 0, 0);
        }
    }
    __syncthreads();

    // Phase 3: epilogue -> fp16 stage (reuse A region) -> coalesced store
    _Float16* st = smem;  // [CT][SLD]
#pragma unroll
    for (int nt = 0; nt < 8; nt++)
#pragma unroll
        for (int r = 0; r < 4; r++) {
            float v = acc[nt][r];
            if (RELU) v = fmaxf(v, 0.f);
            st[(w * 16 + q * 4 + r) * SLD + nt * 16 + nl] = (_Float16)v;
        }
    __syncthreads();
    {
        const int c   = (t & 15) * 8;
        const int sub = t >> 4;
        for (int it = 0; it < CT / 16; it++) {
            const int ln = it * 16 + sub;
            const int n  = nb + ln;
            if (n < kN)
                *(half8*)&out[(size_t)n * 128 + c] = *(const half8*)&st[ln * SLD + c];
        }
    }
}

// ---------------------------------------------------------------------------
// Fused decoder (fp16 MFMA): hp = z[a]*z[b]; y1 = relu(hp@M1^T+b1);
// y2 = relu(y1@M2^T+b2); out = y2.Wm3 + bm3.  PT=64 pairs/block.
// LDS: hp[64][136] + y1[64][136] fp16 = 34.8 KB -> 4 blocks/CU
// ---------------------------------------------------------------------------
constexpr int PT  = 64;
constexpr int HLD = 136;

__global__ __launch_bounds__(256, 4) void decoder_mfma(
    const _Float16* __restrict__ z,
    const int* __restrict__ pairs,
    const _Float16* __restrict__ M1h, const _Float16* __restrict__ M1e,
    const float* __restrict__ bm1,
    const _Float16* __restrict__ M2h, const _Float16* __restrict__ M2e,
    const float* __restrict__ bm2,
    const float* __restrict__ Wm3, const float* __restrict__ bm3,
    float* __restrict__ outv)
{
    __shared__ __align__(16) _Float16 hp[PT * HLD];
    __shared__ __align__(16) _Float16 y1[PT * HLD];
    const int t  = threadIdx.x;
    const int pb = blockIdx.x * PT;

    // P1: hp = z[a] * z[b]
    {
        const int c   = (t & 15) * 8;
        const int sub = t >> 4;
        for (int it = 0; it < PT / 16; it++) {
            const int lp = it * 16 + sub;
            const int gp = pb + lp;
            half8 v;
#pragma unroll
            for (int u = 0; u < 8; u++) v[u] = (_Float16)0.f;
            if (gp < kP) {
                const int a = pairs[gp * 2];
                const int b = pairs[gp * 2 + 1];
                const half8 za = *(const half8*)&z[(size_t)a * 128 + c];
                const half8 zb = *(const half8*)&z[(size_t)b * 128 + c];
#pragma unroll
                for (int u = 0; u < 8; u++) v[u] = (_Float16)((float)za[u] * (float)zb[u]);
            }
            *(half8*)&hp[lp * HLD + c] = v;
        }
    }
    __syncthreads();

    const int w  = t >> 6;
    const int l  = t & 63;
    const int nl = l & 15;
    const int q  = l >> 4;

    // L1: y1 = relu(hp @ M1^T + bm1)  [64 x 128], K=128
    {
        float4v acc[8];
#pragma unroll
        for (int nt = 0; nt < 8; nt++) {
            const float b = bm1[nt * 16 + nl];
            acc[nt][0] = b; acc[nt][1] = b; acc[nt][2] = b; acc[nt][3] = b;
        }
#pragma unroll
        for (int kt = 0; kt < 4; kt++) {
            const half8 a = *(const half8*)&hp[(w * 16 + nl) * HLD + kt * 32 + q * 8];
#pragma unroll
            for (int nt = 0; nt < 8; nt++) {
                const int widx = (nt * 16 + nl) * 128 + kt * 32 + q * 8;
                const half8 bh = *(const half8*)&M1h[widx];
                const half8 be = *(const half8*)&M1e[widx];
                acc[nt] = __builtin_amdgcn_mfma_f32_16x16x32_f16(a, bh, acc[nt], 0, 0, 0);
                acc[nt] = __builtin_amdgcn_mfma_f32_16x16x32_f16(a, be, acc[nt], 0, 0, 0);
            }
        }
#pragma unroll
        for (int nt = 0; nt < 8; nt++)
#pragma unroll
            for (int r = 0; r < 4; r++)
                y1[(w * 16 + q * 4 + r) * HLD + nt * 16 + nl] =
                    (_Float16)fmaxf(acc[nt][r], 0.f);
    }
    __syncthreads();

    // L2: y2 = relu(y1 @ M2^T + bm2)  [64 x 64], K=128 -> into hp region
    {
        float4v acc[4];
#pragma unroll
        for (int nt = 0; nt < 4; nt++) {
            const float b = bm2[nt * 16 + nl];
            acc[nt][0] = b; acc[nt][1] = b; acc[nt][2] = b; acc[nt][3] = b;
        }
#pragma unroll
        for (int kt = 0; kt < 4; kt++) {
            const half8 a = *(const half8*)&y1[(w * 16 + nl) * HLD + kt * 32 + q * 8];
#pragma unroll
            for (int nt = 0; nt < 4; nt++) {
                const int widx = (nt * 16 + nl) * 128 + kt * 32 + q * 8;
                const half8 bh = *(const half8*)&M2h[widx];
                const half8 be = *(const half8*)&M2e[widx];
                acc[nt] = __builtin_amdgcn_mfma_f32_16x16x32_f16(a, bh, acc[nt], 0, 0, 0);
                acc[nt] = __builtin_amdgcn_mfma_f32_16x16x32_f16(a, be, acc[nt], 0, 0, 0);
            }
        }
#pragma unroll
        for (int nt = 0; nt < 4; nt++)
#pragma unroll
            for (int r = 0; r < 4; r++)
                hp[(w * 16 + q * 4 + r) * HLD + nt * 16 + nl] =
                    (_Float16)fmaxf(acc[nt][r], 0.f);
    }
    __syncthreads();

    // L3: out = y2 . Wm3 + bm3  (4 lanes/pair, shuffle reduce)
    {
        const int p  = t >> 2;
        const int qq = t & 3;
        float s = 0.f;
#pragma unroll
        for (int dd = 0; dd < 16; dd++) {
            const int d = qq * 16 + dd;
            s += (float)hp[p * HLD + d] * Wm3[d];
        }
        s += __shfl_xor(s, 1);
        s += __shfl_xor(s, 2);
        const int gp = pb + p;
        if (qq == 0 && gp < kP) outv[gp] = s + bm3[0];
    }
}

// ---------------------------------------------------------------------------
extern "C" void kernel_launch(void* const* d_in, const int* in_sizes, int n_in,
                              void* d_out, int out_size, void* d_ws, size_t ws_size,
                              hipStream_t stream) {
    const float* x   = (const float*)d_in[0];
    const int*   src = (const int*)d_in[1];
    const int*   dst = src + kE;
    const int*   ep  = (const int*)d_in[2];
    const float* W1l = (const float*)d_in[3];
    const float* b1l = (const float*)d_in[4];
    const float* W1r = (const float*)d_in[5];
    const float* W2l = (const float*)d_in[6];
    const float* b2l = (const float*)d_in[7];
    const float* W2r = (const float*)d_in[8];
    const float* Wm1 = (const float*)d_in[9];
    const float* bm1 = (const float*)d_in[10];
    const float* Wm2 = (const float*)d_in[11];
    const float* bm2 = (const float*)d_in[12];
    const float* Wm3 = (const float*)d_in[13];
    const float* bm3 = (const float*)d_in[14];
    float* outv = (float*)d_out;

    char* ws = (char*)d_ws;
    size_t off = 0;
    auto alloc = [&](size_t bytes) -> void* {
        void* p = ws + off;
        off += bytes;
        off = (off + 255) & ~(size_t)255;
        return p;
    };
    int*      deg       = (int*)alloc((size_t)kN * 4);
    int*      row_start = (int*)alloc((size_t)(kN + 1) * 4);
    int*      cursor    = (int*)alloc((size_t)kN * 4);
    int*      bsum      = (int*)alloc(512 * 4);
    int*      boff      = (int*)alloc(512 * 4);
    int*      srcs      = (int*)alloc((size_t)kE * 4);
    _Float16* xh        = (_Float16*)alloc((size_t)kN * 128 * 2);
    _Float16* hh        = (_Float16*)alloc((size_t)kN * 128 * 2);
    _Float16* zh        = (_Float16*)alloc((size_t)kN * 128 * 2);
    _Float16* CW1h      = (_Float16*)alloc(128 * 256 * 2);
    _Float16* CW1e      = (_Float16*)alloc(128 * 256 * 2);
    _Float16* CW2h      = (_Float16*)alloc(128 * 256 * 2);
    _Float16* CW2e      = (_Float16*)alloc(128 * 256 * 2);
    _Float16* M1h       = (_Float16*)alloc(128 * 128 * 2);
    _Float16* M1e       = (_Float16*)alloc(128 * 128 * 2);
    _Float16* M2h       = (_Float16*)alloc(64 * 128 * 2);
    _Float16* M2e       = (_Float16*)alloc(64 * 128 * 2);

    // CSR build
    hipMemsetAsync(deg, 0, (size_t)kN * sizeof(int), stream);
    deg_kernel<<<(kE + 255) / 256, 256, 0, stream>>>(dst, deg);
    scan_block_sums<<<NBS, 256, 0, stream>>>(deg, bsum);
    scan_bsums<<<1, 512, 0, stream>>>(bsum, boff);
    scan_write<<<NBS, 256, 0, stream>>>(deg, boff, row_start, cursor);
    fill_kernel<<<(kE + 255) / 256, 256, 0, stream>>>(src, dst, cursor, srcs);

    // Prep: fp16 conversions
    cvt_x_kernel<<<(kN * 128 / 8 + 255) / 256, 256, 0, stream>>>(x, xh);
    cvt_w_kernel<<<352, 256, 0, stream>>>(W1l, W1r, W2l, W2r, Wm1, Wm2,
                                          CW1h, CW1e, CW2h, CW2e, M1h, M1e, M2h, M2e);

    // Two SAGEConv layers (fp16 MFMA)
    const int convGrid = (kN + CT - 1) / CT;
    conv_mfma<true><<<convGrid, 256, 0, stream>>>(xh, row_start, srcs, CW1h, CW1e, b1l, hh);
    conv_mfma<false><<<convGrid, 256, 0, stream>>>(hh, row_start, srcs, CW2h, CW2e, b2l, zh);

    // Fused MLP decoder (fp16 MFMA)
    decoder_mfma<<<(kP + PT - 1) / PT, 256, 0, stream>>>(
        zh, ep, M1h, M1e, bm1, M2h, M2e, bm2, Wm3, bm3, outv);
}